// Round 8
// baseline (188.824 us; speedup 1.0000x reference)
//
#include <hip/hip_runtime.h>
#include <cfloat>

#define NEG_INF_F (-1e30f)

constexpr int BB = 8, SS = 4096, HH = 1024;
constexpr int TOTAL = BB * SS;        // 32768 rows
constexpr int MAXLEN = 30;
constexpr int BLK_PER_BATCH = SS / 4; // 1024 blocks per batch (4 rows/block)

// ---------- packed u64 key: (sortable-float << 32) | (0xFFFFFFFF - idx) ----------
// Higher key = higher value, then lower flat index (jax top_k tie-break).
__device__ __forceinline__ unsigned long long pack_key(float v, unsigned idx) {
  unsigned u = __float_as_uint(v);
  u = (u & 0x80000000u) ? ~u : (u | 0x80000000u);
  return ((unsigned long long)u << 32) | (unsigned long long)(0xFFFFFFFFu - idx);
}

// Sorted-descending 5-key insert with early exit (keys unique, 0 = sentinel).
__device__ __forceinline__ void k5_insert(unsigned long long k[5], unsigned long long nk) {
  if (nk <= k[4]) return;
  k[4] = nk;
  unsigned long long t;
  if (k[4] > k[3]) { t = k[3]; k[3] = k[4]; k[4] = t; }
  if (k[3] > k[2]) { t = k[2]; k[2] = k[3]; k[3] = t; }
  if (k[2] > k[1]) { t = k[1]; k[1] = k[2]; k[2] = t; }
  if (k[1] > k[0]) { t = k[0]; k[0] = k[1]; k[1] = t; }
}

// Wave-wide top-5 via 5 argmax rounds on u64 keys; result same in all lanes.
__device__ __forceinline__ void wave_top5_u64(unsigned long long k[5],
                                              unsigned long long r[5]) {
#pragma unroll
  for (int q = 0; q < 5; ++q) {
    unsigned long long m = k[0];
    if (k[1] > m) m = k[1];
    if (k[2] > m) m = k[2];
    if (k[3] > m) m = k[3];
    if (k[4] > m) m = k[4];
#pragma unroll
    for (int off = 1; off < 64; off <<= 1) {
      unsigned long long o = __shfl_xor(m, off);
      if (o > m) m = o;
    }
    r[q] = m;
#pragma unroll
    for (int p = 0; p < 5; ++p)
      if (k[p] == m) k[p] = 0ull;  // keys unique; invalidate winner
  }
}

__device__ __forceinline__ float agent_load(const float* p) {
  return __hip_atomic_load(p, __ATOMIC_RELAXED, __HIP_MEMORY_SCOPE_AGENT);
}
__device__ __forceinline__ void agent_store(float* p, float v) {
  __hip_atomic_store(p, v, __ATOMIC_RELAXED, __HIP_MEMORY_SCOPE_AGENT);
}

// ---------------- fused kernel: GEMV + masked logits + ticketed per-batch topk ----
// 8192 blocks x 256 threads, 4 rows/block (one wave per row). Batches interleaved
// across blockIdx (b = blockIdx&7) so all 8 batch-tails fire near stream end and
// overlap each other. The last-ticket block of each batch computes that batch's
// top-5 from an agent-coherent mirror of the logits (cross-XCD safe).
__global__ __launch_bounds__(256, 6) void fused_kernel(
    const float* __restrict__ X,     // (B*S, H)
    const float* __restrict__ mask,  // (B*S)
    const float* __restrict__ W,     // (H, 2)
    const float* __restrict__ bqa,   // (2)
    float* __restrict__ out,         // start | end | top_start | top_end
    float* __restrict__ mir,         // ws mirror: start | end (agent-coherent)
    unsigned* __restrict__ cnt) {    // (BB) ticket counters, memset to 0 per launch
  const int lane = threadIdx.x & 63;
  const int w = (int)threadIdx.x >> 6;
  const int b = blockIdx.x & (BB - 1);
  const int chunk = blockIdx.x >> 3;
  const int row = b * SS + chunk * 4 + w;

  // ---------- GEMV (measured roofline ~6.7 TB/s in R1-R3, math unchanged) ----------
  {
    const float* rp = X + (size_t)row * HH;
    float s0 = 0.f, s1 = 0.f;
#pragma unroll
    for (int kk = 0; kk < HH / 256; ++kk) {
      int h = (kk * 64 + lane) * 4;
      const float4 x   = *reinterpret_cast<const float4*>(rp + h);
      const float4 w01 = *reinterpret_cast<const float4*>(W + 2 * h);
      const float4 w23 = *reinterpret_cast<const float4*>(W + 2 * h + 4);
      s0 += x.x * w01.x + x.y * w01.z + x.z * w23.x + x.w * w23.z;
      s1 += x.x * w01.y + x.y * w01.w + x.z * w23.y + x.w * w23.w;
    }
#pragma unroll
    for (int off = 32; off > 0; off >>= 1) {
      s0 += __shfl_down(s0, off);
      s1 += __shfl_down(s1, off);
    }
    if (lane == 0) {
      float m = mask[row];
      float inv = 1.f - m;
      float r0 = (s0 + bqa[0]) * m + inv * NEG_INF_F;
      float r1 = (s1 + bqa[1]) * m + inv * NEG_INF_F;
      out[row] = r0;
      out[TOTAL + row] = r1;
      agent_store(&mir[row], r0);          // cross-XCD visible copy
      agent_store(&mir[TOTAL + row], r1);
    }
  }

  // ---------- ticket: __syncthreads drains vmcnt (stores complete) before RMW ----
  __shared__ unsigned s_old;
  __syncthreads();
  if (threadIdx.x == 0)
    s_old = __hip_atomic_fetch_add(&cnt[b], 1u, __ATOMIC_RELAXED,
                                   __HIP_MEMORY_SCOPE_AGENT);
  __syncthreads();
  if (s_old != (unsigned)(BLK_PER_BATCH - 1)) return;

  // ---------- tail: this block is last for batch b -> full banded top-5 ----------
  __shared__ float lse[SS];               // batch's end-logits staged in LDS (16 KB)
  __shared__ unsigned long long sk[4 * 5];
  const float* ms = mir + (size_t)b * SS;
  const float* me = mir + TOTAL + (size_t)b * SS;

  for (int t = (int)threadIdx.x; t < SS; t += 256) lse[t] = agent_load(me + t);
  __syncthreads();

  unsigned long long k5[5] = {0, 0, 0, 0, 0};
  // special diagonal spans (1,1),(2,2),(3,3)
  if (threadIdx.x >= 1 && threadIdx.x <= 3) {
    int i = (int)threadIdx.x;
    k5_insert(k5, pack_key(agent_load(ms + i) + lse[i], (unsigned)(i * SS + i)));
  }
  // rows i in [4, S): window j in [i, i+30) ∩ [0, S)
  for (int it = 0; it < 16; ++it) {
    int i = 4 + (int)threadIdx.x + 256 * it;
    if (i >= SS) break;
    float sv = agent_load(ms + i);
    unsigned base = (unsigned)(i * SS + i);
#pragma unroll
    for (int c = 0; c < MAXLEN; ++c) {
      int j = i + c;
      if (j < SS) k5_insert(k5, pack_key(sv + lse[j], base + c));
    }
  }

  unsigned long long r5[5];
  wave_top5_u64(k5, r5);
  if (lane == 0) {
#pragma unroll
    for (int q = 0; q < 5; ++q) sk[w * 5 + q] = r5[q];
  }
  __syncthreads();
  if (w == 0) {
    unsigned long long m5[5] = {0, 0, 0, 0, 0};
    if (lane < 20) m5[0] = sk[lane];
    unsigned long long f5[5];
    wave_top5_u64(m5, f5);
    if (lane == 0) {
      float* ts = out + 2 * (size_t)TOTAL;  // top_start region
      float* te = ts + BB * 5;              // top_end region
#pragma unroll
      for (int q = 0; q < 5; ++q) {
        unsigned idx = 0xFFFFFFFFu - (unsigned)(f5[q] & 0xFFFFFFFFull);
        ts[b * 5 + q] = (float)(idx >> 12);        // idx / S  (S=4096)
        te[b * 5 + q] = (float)(idx & (SS - 1));   // idx % S
      }
    }
  }
}

// ---------------- fallback (ws too small): proven R3 3-kernel path ----------------
__device__ __forceinline__ bool t5_better(float av, int ai, float bv, int bi) {
  return av > bv || (av == bv && ai < bi);
}
__device__ __forceinline__ void t5_insert(float v[5], int id[5], float nv, int ni) {
  if (!t5_better(nv, ni, v[4], id[4])) return;
  v[4] = nv; id[4] = ni;
#pragma unroll
  for (int q = 4; q > 0; --q) {
    if (t5_better(v[q], id[q], v[q - 1], id[q - 1])) {
      float tv = v[q]; v[q] = v[q - 1]; v[q - 1] = tv;
      int ti = id[q]; id[q] = id[q - 1]; id[q - 1] = ti;
    }
  }
}
__device__ __forceinline__ void t5_init(float v[5], int id[5]) {
#pragma unroll
  for (int q = 0; q < 5; ++q) { v[q] = -FLT_MAX; id[q] = 0x7fffffff; }
}
__device__ __forceinline__ void wave_top5f(float v[5], int id[5], float rv[5], int rid[5]) {
#pragma unroll
  for (int r = 0; r < 5; ++r) {
    float bv = v[0]; int bi = id[0];
#pragma unroll
    for (int q = 1; q < 5; ++q)
      if (t5_better(v[q], id[q], bv, bi)) { bv = v[q]; bi = id[q]; }
#pragma unroll
    for (int off = 1; off < 64; off <<= 1) {
      float ov = __shfl_xor(bv, off);
      int oi = __shfl_xor(bi, off);
      if (t5_better(ov, oi, bv, bi)) { bv = ov; bi = oi; }
    }
    rv[r] = bv; rid[r] = bi;
#pragma unroll
    for (int q = 0; q < 5; ++q)
      if (id[q] == bi) v[q] = -FLT_MAX;
  }
}
__global__ __launch_bounds__(256) void qa_logits_kernel(
    const float* __restrict__ X, const float* __restrict__ mask,
    const float* __restrict__ W, const float* __restrict__ bqa,
    float* __restrict__ out) {
  int row  = (int)((blockIdx.x * (size_t)blockDim.x + threadIdx.x) >> 6);
  int lane = threadIdx.x & 63;
  if (row >= TOTAL) return;
  const float* rp = X + (size_t)row * HH;
  float s0 = 0.f, s1 = 0.f;
#pragma unroll
  for (int k = 0; k < HH / 256; ++k) {
    int h = (k * 64 + lane) * 4;
    const float4 x   = *reinterpret_cast<const float4*>(rp + h);
    const float4 w01 = *reinterpret_cast<const float4*>(W + 2 * h);
    const float4 w23 = *reinterpret_cast<const float4*>(W + 2 * h + 4);
    s0 += x.x * w01.x + x.y * w01.z + x.z * w23.x + x.w * w23.z;
    s1 += x.x * w01.y + x.y * w01.w + x.z * w23.y + x.w * w23.w;
  }
#pragma unroll
  for (int off = 32; off > 0; off >>= 1) {
    s0 += __shfl_down(s0, off);
    s1 += __shfl_down(s1, off);
  }
  if (lane == 0) {
    float m = mask[row];
    float inv = 1.f - m;
    out[row]         = (s0 + bqa[0]) * m + inv * NEG_INF_F;
    out[TOTAL + row] = (s1 + bqa[1]) * m + inv * NEG_INF_F;
  }
}
__global__ __launch_bounds__(64) void topk_stage1(
    const float* __restrict__ logits, float* __restrict__ wv_out, int* __restrict__ wi_out) {
  int blocks_per_b = SS / 64;
  int b  = blockIdx.x / blocks_per_b;
  int rb = blockIdx.x % blocks_per_b;
  int lane = (int)threadIdx.x;
  int i = rb * 64 + lane;
  const float* st = logits + (size_t)b * SS;
  const float* en = logits + (size_t)(BB + b) * SS;
  float v[5]; int id[5];
  t5_init(v, id);
  if (i >= 4) {
    float si = st[i];
    float e[MAXLEN];
#pragma unroll
    for (int c = 0; c < MAXLEN; ++c) {
      int j = i + c;
      e[c] = (j < SS) ? en[j] : NEG_INF_F;
    }
    int base = i * SS + i;
#pragma unroll
    for (int c = 0; c < MAXLEN; ++c) t5_insert(v, id, si + e[c], base + c);
  } else if (i >= 1) {
    t5_insert(v, id, st[i] + en[i], i * SS + i);
  }
  float rv[5]; int rid[5];
  wave_top5f(v, id, rv, rid);
  if (lane == 0) {
#pragma unroll
    for (int q = 0; q < 5; ++q) {
      wv_out[blockIdx.x * 5 + q] = rv[q];
      wi_out[blockIdx.x * 5 + q] = rid[q];
    }
  }
}
__global__ __launch_bounds__(64) void topk_stage2(
    const float* __restrict__ wv_in, const int* __restrict__ wi_in, float* __restrict__ out) {
  int b = blockIdx.x;
  int lane = (int)threadIdx.x;
  int n = (SS / 64) * 5;
  const float* wv = wv_in + (size_t)b * n;
  const int*   wi = wi_in + (size_t)b * n;
  float v[5]; int id[5];
  t5_init(v, id);
#pragma unroll 5
  for (int c = lane; c < n; c += 64) t5_insert(v, id, wv[c], wi[c]);
  float rv[5]; int rid[5];
  wave_top5f(v, id, rv, rid);
  if (lane == 0) {
    float* ts = out + 2 * (size_t)TOTAL;
    float* te = ts + BB * 5;
#pragma unroll
    for (int q = 0; q < 5; ++q) {
      ts[b * 5 + q] = (float)(rid[q] >> 12);
      te[b * 5 + q] = (float)(rid[q] & (SS - 1));
    }
  }
}

extern "C" void kernel_launch(void* const* d_in, const int* in_sizes, int n_in,
                              void* d_out, int out_size, void* d_ws, size_t ws_size,
                              hipStream_t stream) {
  const float* X    = (const float*)d_in[0];  // (B,S,H)
  const float* mask = (const float*)d_in[1];  // (B,S)
  const float* W    = (const float*)d_in[2];  // (H,2)
  const float* bqa  = (const float*)d_in[3];  // (2)
  float* out = (float*)d_out;

  const size_t mir_bytes = (size_t)2 * TOTAL * sizeof(float);  // 256 KB
  const size_t need = mir_bytes + BB * sizeof(unsigned);

  if (ws_size >= need) {
    float* mir = (float*)d_ws;
    unsigned* cnt = (unsigned*)((char*)d_ws + mir_bytes);
    hipMemsetAsync(cnt, 0, BB * sizeof(unsigned), stream);  // fresh tickets per replay
    fused_kernel<<<TOTAL / 4, 256, 0, stream>>>(X, mask, W, bqa, out, mir, cnt);
  } else {
    // proven R3 path
    float* wv_ws = (float*)d_ws;
    int*   wi_ws = (int*)((char*)d_ws + (size_t)BB * (SS / 64) * 5 * sizeof(float));
    qa_logits_kernel<<<TOTAL / 4, 256, 0, stream>>>(X, mask, W, bqa, out);
    topk_stage1<<<BB * (SS / 64), 64, 0, stream>>>(out, wv_ws, wi_ws);
    topk_stage2<<<BB, 64, 0, stream>>>(wv_ws, wi_ws, out);
  }
}

// Round 9
// 36.532 us; speedup vs baseline: 5.1688x; 5.1688x over previous
//
#include <hip/hip_runtime.h>
#include <cfloat>

#define NEG_INF_F (-1e30f)

constexpr int BB = 8, SS = 4096, HH = 1024;
constexpr int TOTAL = BB * SS;   // 32768 rows
constexpr int MAXLEN = 30;
constexpr int RPB = 256;         // stage-1 rows per block
constexpr int BLK_PER_B = SS / RPB;          // 16
constexpr int S1_GRID = BB * BLK_PER_B;      // 128

// ---------------- Kernel 1: QA-head GEMV + masking (proven ~20.5 us) ---------
__global__ __launch_bounds__(256) void qa_logits_kernel(
    const float* __restrict__ X,     // (B*S, H)
    const float* __restrict__ mask,  // (B*S)
    const float* __restrict__ W,     // (H, 2) row-major
    const float* __restrict__ bqa,   // (2)
    float* __restrict__ out) {       // [0,TOTAL): start, [TOTAL,2*TOTAL): end
  int row  = (int)((blockIdx.x * (size_t)blockDim.x + threadIdx.x) >> 6);
  int lane = threadIdx.x & 63;
  if (row >= TOTAL) return;
  const float* rp = X + (size_t)row * HH;
  float s0 = 0.f, s1 = 0.f;
#pragma unroll
  for (int k = 0; k < HH / 256; ++k) {
    int h = (k * 64 + lane) * 4;
    const float4 x   = *reinterpret_cast<const float4*>(rp + h);
    const float4 w01 = *reinterpret_cast<const float4*>(W + 2 * h);
    const float4 w23 = *reinterpret_cast<const float4*>(W + 2 * h + 4);
    s0 += x.x * w01.x + x.y * w01.z + x.z * w23.x + x.w * w23.z;
    s1 += x.x * w01.y + x.y * w01.w + x.z * w23.y + x.w * w23.w;
  }
#pragma unroll
  for (int off = 32; off > 0; off >>= 1) {
    s0 += __shfl_down(s0, off);
    s1 += __shfl_down(s1, off);
  }
  if (lane == 0) {
    float m = mask[row];
    float inv = 1.f - m;
    out[row]         = (s0 + bqa[0]) * m + inv * NEG_INF_F;
    out[TOTAL + row] = (s1 + bqa[1]) * m + inv * NEG_INF_F;
  }
}

// ---------- packed u64 key: (sortable-float << 32) | (~idx) ----------
// Higher key = higher value, then lower flat index (jax top_k tie-break).
// Scheme validated end-to-end in round 8 (passed).
__device__ __forceinline__ unsigned long long pack_key(float v, unsigned idx) {
  unsigned u = __float_as_uint(v);
  u = (u & 0x80000000u) ? ~u : (u | 0x80000000u);
  return ((unsigned long long)u << 32) | (unsigned long long)(0xFFFFFFFFu - idx);
}

// Sorted-descending 5-key insert, early exit (keys unique, 0 = sentinel).
__device__ __forceinline__ void k5_insert(unsigned long long k[5], unsigned long long nk) {
  if (nk <= k[4]) return;
  k[4] = nk;
  unsigned long long t;
  if (k[4] > k[3]) { t = k[3]; k[3] = k[4]; k[4] = t; }
  if (k[3] > k[2]) { t = k[2]; k[2] = k[3]; k[3] = t; }
  if (k[2] > k[1]) { t = k[1]; k[1] = k[2]; k[2] = t; }
  if (k[1] > k[0]) { t = k[0]; k[0] = k[1]; k[1] = t; }
}

// Wave-wide top-5 via 5 argmax rounds on u64 keys; result same in all lanes.
__device__ __forceinline__ void wave_top5_u64(unsigned long long k[5],
                                              unsigned long long r[5]) {
#pragma unroll
  for (int q = 0; q < 5; ++q) {
    unsigned long long m = k[0];
    if (k[1] > m) m = k[1];
    if (k[2] > m) m = k[2];
    if (k[3] > m) m = k[3];
    if (k[4] > m) m = k[4];
#pragma unroll
    for (int off = 1; off < 64; off <<= 1) {
      unsigned long long o = __shfl_xor(m, off);
      if (o > m) m = o;
    }
    r[q] = m;
#pragma unroll
    for (int p = 0; p < 5; ++p)
      if (k[p] == m) k[p] = 0ull;  // keys unique; invalidate winner
  }
}

// ---------------- Stage 1: LDS-staged banded top-5 ----------------
// Block = 256 consecutive rows of one batch. Coalesced float4 stage of
// st[256] + en[286] into LDS (one L2 round trip, OUT of the insert chain),
// then 30 LDS-reads+inserts per thread (lanes read consecutive banks).
__global__ __launch_bounds__(RPB) void topk_stage1(
    const float* __restrict__ logits,      // gemv output (start then end)
    unsigned long long* __restrict__ ws) { // (S1_GRID, 5) block top-5 keys
  const int b  = blockIdx.x / BLK_PER_B;
  const int rb = blockIdx.x % BLK_PER_B;
  const int i0 = rb * RPB;
  const int t  = (int)threadIdx.x;
  const int lane = t & 63;
  const int w = t >> 6;

  __shared__ float s_st[RPB];
  __shared__ float s_en[RPB + 32];       // window tail (+pad)
  __shared__ unsigned long long sk[(RPB / 64) * 5];

  const float* st = logits + (size_t)b * SS + i0;
  const float* en = logits + (size_t)(BB + b) * SS + i0;
  const int n_en = min(SS - i0, RPB + MAXLEN - 1);   // floats of en to stage

  // coalesced stage: 64 float4 for st, ceil(n_en/4) float4 for en
  if (t < RPB / 4)
    *reinterpret_cast<float4*>(&s_st[t * 4]) =
        *reinterpret_cast<const float4*>(st + t * 4);
  else if (t >= 64 && t < 64 + (n_en + 3) / 4) {
    int r = t - 64;
    if (r * 4 + 4 <= n_en)
      *reinterpret_cast<float4*>(&s_en[r * 4]) =
          *reinterpret_cast<const float4*>(en + r * 4);
    else
      for (int c = r * 4; c < n_en; ++c) s_en[c] = en[c];
  }
  __syncthreads();

  unsigned long long k5[5] = {0, 0, 0, 0, 0};
  const int i = i0 + t;
  if (i >= 4) {
    float sv = s_st[t];
    unsigned base = (unsigned)(i * SS + i);
    int cap = n_en - t;  // #valid c (j = i+c < S)
#pragma unroll
    for (int c = 0; c < MAXLEN; ++c)
      if (c < cap) k5_insert(k5, pack_key(sv + s_en[t + c], base + c));
  } else if (i >= 1) {   // spans (1,1),(2,2),(3,3)
    k5_insert(k5, pack_key(s_st[t] + s_en[t], (unsigned)(i * SS + i)));
  }

  unsigned long long r5[5];
  wave_top5_u64(k5, r5);
  if (lane == 0) {
#pragma unroll
    for (int q = 0; q < 5; ++q) sk[w * 5 + q] = r5[q];
  }
  __syncthreads();

  if (w == 0) {  // merge 4 waves * 5 = 20 keys
    unsigned long long m5[5] = {0, 0, 0, 0, 0};
    if (lane < (RPB / 64) * 5) m5[0] = sk[lane];
    unsigned long long f5[5];
    wave_top5_u64(m5, f5);
    if (lane == 0) {
#pragma unroll
      for (int q = 0; q < 5; ++q) ws[blockIdx.x * 5 + q] = f5[q];
    }
  }
}

// ---------------- Stage 2: per-batch merge of 16 blocks * 5 = 80 keys -------
__global__ __launch_bounds__(64) void topk_stage2(
    const unsigned long long* __restrict__ ws,
    float* __restrict__ out) {
  const int b = blockIdx.x;
  const int lane = (int)threadIdx.x;
  const unsigned long long* src = ws + (size_t)b * BLK_PER_B * 5;  // 80 keys

  unsigned long long k5[5] = {0, 0, 0, 0, 0};
  k5[0] = src[lane];                                        // 80 keys: 2/lane
  if (lane < BLK_PER_B * 5 - 64) k5[1] = src[64 + lane];

  unsigned long long r5[5];
  wave_top5_u64(k5, r5);

  if (lane == 0) {
    float* ts = out + 2 * (size_t)TOTAL;  // top_start region
    float* te = ts + BB * 5;              // top_end region
#pragma unroll
    for (int q = 0; q < 5; ++q) {
      unsigned idx = 0xFFFFFFFFu - (unsigned)(r5[q] & 0xFFFFFFFFull);
      ts[b * 5 + q] = (float)(idx >> 12);       // idx / S  (S=4096)
      te[b * 5 + q] = (float)(idx & (SS - 1));  // idx % S
    }
  }
}

extern "C" void kernel_launch(void* const* d_in, const int* in_sizes, int n_in,
                              void* d_out, int out_size, void* d_ws, size_t ws_size,
                              hipStream_t stream) {
  const float* X    = (const float*)d_in[0];  // (B,S,H)
  const float* mask = (const float*)d_in[1];  // (B,S)
  const float* W    = (const float*)d_in[2];  // (H,2)
  const float* bqa  = (const float*)d_in[3];  // (2)
  float* out = (float*)d_out;
  unsigned long long* ws = (unsigned long long*)d_ws;  // S1_GRID*5 u64 = 5 KB

  qa_logits_kernel<<<TOTAL / 4, 256, 0, stream>>>(X, mask, W, bqa, out);
  topk_stage1<<<S1_GRID, RPB, 0, stream>>>(out, ws);
  topk_stage2<<<BB, 64, 0, stream>>>(ws, out);
}